// Round 10
// baseline (538.664 us; speedup 1.0000x reference)
//
#include <hip/hip_runtime.h>
#include <hip/hip_fp16.h>

#define N_NODES 50000
#define N_EDGES 800000
#define HID 64
#define F_EDGE 16
#define LN_EPS 1e-5f
#define SCAN_BLOCKS ((N_NODES + 255) / 256)   // 196

typedef float f4_native __attribute__((ext_vector_type(4)));

// ---------------- utility: 64-lane wave reduction ----------------
__device__ inline float wave_sum64(float v) {
    #pragma unroll
    for (int o = 32; o > 0; o >>= 1) v += __shfl_xor(v, o, 64);
    return v;
}

// ---------------- CSR build ----------------
__global__ void k_zero_cnt(int* __restrict__ cnt) {
    int i = blockIdx.x * blockDim.x + threadIdx.x;
    if (i < N_NODES) cnt[i] = 0;
}

__global__ void k_count(const int* __restrict__ dst, int* __restrict__ cnt) {
    int e = blockIdx.x * blockDim.x + threadIdx.x;
    if (e < N_EDGES) atomicAdd(&cnt[dst[e]], 1);
}

// stage 1: per-block exclusive scan into row_ptr, block sums into bsum; fused dinv
__global__ void k_scan1(const int* __restrict__ cnt, int* __restrict__ row_ptr,
                        int* __restrict__ bsum, float* __restrict__ dinv) {
    __shared__ int wsum[4];
    int tid = threadIdx.x, lane = tid & 63, w = tid >> 6;
    int i = blockIdx.x * 256 + tid;
    int v = (i < N_NODES) ? cnt[i] : 0;
    if (i < N_NODES) dinv[i] = rsqrtf((float)v + 1.0f);
    int isc = v;
    #pragma unroll
    for (int o = 1; o < 64; o <<= 1) {
        int n = __shfl_up(isc, o, 64);
        if (lane >= o) isc += n;
    }
    if (lane == 63) wsum[w] = isc;
    __syncthreads();
    int woff = 0;
    #pragma unroll
    for (int k = 0; k < 4; k++) woff += (k < w) ? wsum[k] : 0;
    if (i < N_NODES) row_ptr[i] = woff + isc - v;
    if (tid == 255) bsum[blockIdx.x] = woff + isc;
}

// stage 2: single block scans the block sums -> exclusive boff
__global__ void k_scan2(const int* __restrict__ bsum, int* __restrict__ boff) {
    __shared__ int wsum[4];
    int tid = threadIdx.x, lane = tid & 63, w = tid >> 6;
    int v = (tid < SCAN_BLOCKS) ? bsum[tid] : 0;
    int isc = v;
    #pragma unroll
    for (int o = 1; o < 64; o <<= 1) {
        int n = __shfl_up(isc, o, 64);
        if (lane >= o) isc += n;
    }
    if (lane == 63) wsum[w] = isc;
    __syncthreads();
    int woff = 0;
    #pragma unroll
    for (int k = 0; k < 4; k++) woff += (k < w) ? wsum[k] : 0;
    if (tid < SCAN_BLOCKS) boff[tid] = woff + isc - v;
}

// stage 3: apply block offsets, init cursor
__global__ void k_scan3(int* __restrict__ row_ptr, const int* __restrict__ boff,
                        int* __restrict__ cursor) {
    int i = blockIdx.x * blockDim.x + threadIdx.x;
    if (i < N_NODES) {
        int r = row_ptr[i] + boff[i >> 8];
        row_ptr[i] = r;
        cursor[i] = r;
    }
    if (i == 0) row_ptr[N_NODES] = N_EDGES;
}

// fill: single random 4B store per edge
__global__ void k_fill(const int* __restrict__ src, const int* __restrict__ dst,
                       int* __restrict__ cursor, int* __restrict__ col) {
    int e = blockIdx.x * blockDim.x + threadIdx.x;
    if (e < N_EDGES) {
        int s = src[e], d = dst[e];
        int pos = atomicAdd(&cursor[d], 1);
        col[pos] = s;
    }
}

// ---------------- xs = fp16(dinv * x), channel-split halves ----------------
__global__ void k_xs_init(const float* __restrict__ x, const float* __restrict__ dinv,
                          __half* __restrict__ xsA, __half* __restrict__ xsB) {
    int i = blockIdx.x * blockDim.x + threadIdx.x;
    if (i < N_NODES * 64) {
        int node = i >> 6, c = i & 63;
        __half v = __float2half_rn(x[i] * dinv[node]);
        if (c < 32) xsA[node * 32 + c] = v;
        else        xsB[node * 32 + (c - 32)] = v;
    }
}

// ---------------- gather: agg[d] = dinv[d]*(sum xs[s] + xs[d]), half-split ----------------
// One wave handles one (node, half): 16 edge-slots x 4 lanes x 16 B (8 halves).
// half steered by blockIdx so (assumed b%8 round-robin) XCDs 0-3 serve half A,
// 4-7 half B -> each XCD's random set is 3.2 MB, L2-resident.
__global__ void __launch_bounds__(256)
k_gather_agg(const __half* __restrict__ xsA, const __half* __restrict__ xsB,
             const float* __restrict__ dinv,
             const int* __restrict__ row_ptr, const int* __restrict__ col,
             float* __restrict__ agg) {
    int b = blockIdx.x;
    int half = (b >> 2) & 1;
    int nodeBlock = (b >> 3) * 4 + (b & 3);   // 0..12499
    int wave = threadIdx.x >> 6, lane = threadIdx.x & 63;
    int node = nodeBlock * 4 + wave;
    if (node >= N_NODES) return;
    int n0 = __builtin_amdgcn_readfirstlane(node);
    int slot = lane >> 2;    // 0..15 edge slots
    int cq = lane & 3;       // channel quad: 8 halves = 16 B
    const __half* xsH = half ? xsB : xsA;
    const float4* x4 = (const float4*)xsH;    // row = 4 x float4 (64 B)

    float acc[8];
    #pragma unroll
    for (int u = 0; u < 8; u++) acc[u] = 0.0f;

    // self-loop row on slot 0 (weight 1: xs pre-scaled by dinv)
    if (slot == 0) {
        float4 raw = x4[(size_t)n0 * 4 + cq];
        const __half2* hp = (const __half2*)&raw;
        float2 f0 = __half22float2(hp[0]);
        float2 f1 = __half22float2(hp[1]);
        float2 f2 = __half22float2(hp[2]);
        float2 f3 = __half22float2(hp[3]);
        acc[0] = f0.x; acc[1] = f0.y; acc[2] = f1.x; acc[3] = f1.y;
        acc[4] = f2.x; acc[5] = f2.y; acc[6] = f3.x; acc[7] = f3.y;
    }

    int beg = row_ptr[n0], end = row_ptr[n0 + 1];
    int deg = end - beg;

    int cL = 0;
    if (lane < deg) cL = __builtin_nontemporal_load(&col[beg + lane]);
    int steps = (min(deg, 64) + 15) >> 4;

    #pragma unroll 2
    for (int st = 0; st < steps; st++) {
        int idx = 16 * st + slot;
        int s = __shfl(cL, idx, 64);            // 0 for masked lanes -> safe addr
        float m = (idx < deg) ? 1.0f : 0.0f;
        float4 raw = x4[(size_t)s * 4 + cq];
        const __half2* hp = (const __half2*)&raw;
        float2 f0 = __half22float2(hp[0]);
        float2 f1 = __half22float2(hp[1]);
        float2 f2 = __half22float2(hp[2]);
        float2 f3 = __half22float2(hp[3]);
        acc[0] = fmaf(f0.x, m, acc[0]); acc[1] = fmaf(f0.y, m, acc[1]);
        acc[2] = fmaf(f1.x, m, acc[2]); acc[3] = fmaf(f1.y, m, acc[3]);
        acc[4] = fmaf(f2.x, m, acc[4]); acc[5] = fmaf(f2.y, m, acc[5]);
        acc[6] = fmaf(f3.x, m, acc[6]); acc[7] = fmaf(f3.y, m, acc[7]);
    }
    // tail deg>64 (rare)
    for (int j = beg + 64 + slot; j < end; j += 16) {
        int s = col[j];
        float4 raw = x4[(size_t)s * 4 + cq];
        const __half2* hp = (const __half2*)&raw;
        float2 f0 = __half22float2(hp[0]);
        float2 f1 = __half22float2(hp[1]);
        float2 f2 = __half22float2(hp[2]);
        float2 f3 = __half22float2(hp[3]);
        acc[0] += f0.x; acc[1] += f0.y; acc[2] += f1.x; acc[3] += f1.y;
        acc[4] += f2.x; acc[5] += f2.y; acc[6] += f3.x; acc[7] += f3.y;
    }

    // reduce across 16 slots (lane bits 2..5)
    #pragma unroll
    for (int o = 4; o <= 32; o <<= 1) {
        #pragma unroll
        for (int u = 0; u < 8; u++) acc[u] += __shfl_xor(acc[u], o, 64);
    }

    if (slot == 0) {
        float di = dinv[n0];
        f4_native y0, y1;
        y0.x = acc[0] * di; y0.y = acc[1] * di; y0.z = acc[2] * di; y0.w = acc[3] * di;
        y1.x = acc[4] * di; y1.y = acc[5] * di; y1.z = acc[6] * di; y1.w = acc[7] * di;
        f4_native* a4 = (f4_native*)agg;
        size_t base = (size_t)n0 * 16 + half * 8 + cq * 2;
        __builtin_nontemporal_store(y0, &a4[base]);
        __builtin_nontemporal_store(y1, &a4[base + 1]);
    }
}

// ---------------- fused: y = relu(LN(agg @ W + cb)); out: split fp16 xs or fp32 h ----------------
__global__ void __launch_bounds__(256)
k_gemm_ln(const float* __restrict__ agg, const float* __restrict__ W,
          const float* __restrict__ cb, const float* __restrict__ g,
          const float* __restrict__ b, const float* __restrict__ dinv,
          __half* __restrict__ xsA, __half* __restrict__ xsB,
          float* __restrict__ h_out) {
    int lane = threadIdx.x & 63;
    int wid = (blockIdx.x * blockDim.x + threadIdx.x) >> 6;
    int nwaves = (gridDim.x * blockDim.x) >> 6;
    float w[64];
    #pragma unroll
    for (int k = 0; k < 64; k++) w[k] = W[k * 64 + lane];
    float cbl = cb[lane], gl = g[lane], bl = b[lane];
    for (int row = wid; row < N_NODES; row += nwaves) {
        int r = __builtin_amdgcn_readfirstlane(row);
        const float* xr = agg + r * 64;
        float acc = cbl;
        #pragma unroll
        for (int k = 0; k < 64; k++) acc = fmaf(xr[k], w[k], acc);
        float mu = wave_sum64(acc) * (1.0f / 64.0f);
        float d = acc - mu;
        float var = wave_sum64(d * d) * (1.0f / 64.0f);
        float y = fmaxf(fmaf(d * rsqrtf(var + LN_EPS), gl, bl), 0.0f);
        if (xsA) {
            __half v = __float2half_rn(y * dinv[r]);
            if (lane < 32) xsA[r * 32 + lane] = v;
            else           xsB[r * 32 + (lane & 31)] = v;
        } else {
            h_out[r * 64 + lane] = y;
        }
    }
}

// fused P/Q (fp16 out): first half of blocks -> P = h@W1a + b1, second half -> Q = h@W1b
__global__ void __launch_bounds__(256)
k_gemm_pq(const float* __restrict__ hin, const float* __restrict__ Wp,
          const float* __restrict__ bp, const float* __restrict__ Wq,
          __half* __restrict__ P, __half* __restrict__ Q) {
    int half_g = gridDim.x >> 1;
    bool isQ = (blockIdx.x >= half_g);
    const float* W = isQ ? Wq : Wp;
    __half* out = isQ ? Q : P;
    int lane = threadIdx.x & 63;
    int bid = isQ ? (blockIdx.x - half_g) : blockIdx.x;
    int wid = (bid * blockDim.x + threadIdx.x) >> 6;
    int nwaves = (half_g * blockDim.x) >> 6;
    float w[64];
    #pragma unroll
    for (int k = 0; k < 64; k++) w[k] = W[k * 64 + lane];
    float binit = isQ ? 0.0f : bp[lane];
    for (int row = wid; row < N_NODES; row += nwaves) {
        int r = __builtin_amdgcn_readfirstlane(row);
        const float* xr = hin + r * 64;
        float acc = binit;
        #pragma unroll
        for (int k = 0; k < 64; k++) acc = fmaf(xr[k], w[k], acc);
        out[r * 64 + lane] = __float2half_rn(acc);
    }
}

// ---------------- decoder: original edge order, fp16 P/Q gathers ----------------
// RULE: acc[]/acc2[] indices compile-time constant (no scratch spill).
__global__ void __launch_bounds__(256)
k_decoder(const __half* __restrict__ P, const __half* __restrict__ Q,
          const int* __restrict__ src, const int* __restrict__ dst,
          const float* __restrict__ attr,
          const float* __restrict__ W1c,
          const float* __restrict__ W2, const float* __restrict__ b2,
          const float* __restrict__ W3, const float* __restrict__ b3,
          float* __restrict__ out) {
    int e = blockIdx.x * blockDim.x + threadIdx.x;
    if (e >= N_EDGES) return;
    int s = src[e], d = dst[e];

    const float4* ap = (const float4*)(attr + (size_t)e * 16);
    float4 av0 = ap[0], av1 = ap[1], av2 = ap[2], av3 = ap[3];

    float acc[64];
    const float4* Pp = (const float4*)(P + (size_t)s * 64);
    const float4* Qp = (const float4*)(Q + (size_t)d * 64);
    #pragma unroll
    for (int c = 0; c < 8; c++) {
        float4 pv = Pp[c], qv = Qp[c];
        const __half2* ph = (const __half2*)&pv;
        const __half2* qh = (const __half2*)&qv;
        #pragma unroll
        for (int u = 0; u < 4; u++) {
            float2 pf = __half22float2(ph[u]);
            float2 qf = __half22float2(qh[u]);
            acc[8 * c + 2 * u]     = pf.x + qf.x;
            acc[8 * c + 2 * u + 1] = pf.y + qf.y;
        }
    }

    #pragma unroll
    for (int j = 0; j < 64; j++) {
        float a = acc[j];
        a = fmaf(av0.x, W1c[0 * 64 + j], a);
        a = fmaf(av0.y, W1c[1 * 64 + j], a);
        a = fmaf(av0.z, W1c[2 * 64 + j], a);
        a = fmaf(av0.w, W1c[3 * 64 + j], a);
        a = fmaf(av1.x, W1c[4 * 64 + j], a);
        a = fmaf(av1.y, W1c[5 * 64 + j], a);
        a = fmaf(av1.z, W1c[6 * 64 + j], a);
        a = fmaf(av1.w, W1c[7 * 64 + j], a);
        a = fmaf(av2.x, W1c[8 * 64 + j], a);
        a = fmaf(av2.y, W1c[9 * 64 + j], a);
        a = fmaf(av2.z, W1c[10 * 64 + j], a);
        a = fmaf(av2.w, W1c[11 * 64 + j], a);
        a = fmaf(av3.x, W1c[12 * 64 + j], a);
        a = fmaf(av3.y, W1c[13 * 64 + j], a);
        a = fmaf(av3.z, W1c[14 * 64 + j], a);
        a = fmaf(av3.w, W1c[15 * 64 + j], a);
        acc[j] = fmaxf(a, 0.0f);
    }

    float acc2[32];
    #pragma unroll
    for (int j = 0; j < 32; j++) acc2[j] = b2[j];
    #pragma unroll
    for (int k = 0; k < 64; k++) {
        float hk = acc[k];
        #pragma unroll
        for (int j = 0; j < 32; j++)
            acc2[j] = fmaf(hk, W2[k * 32 + j], acc2[j]);
    }

    float o = b3[0];
    #pragma unroll
    for (int j = 0; j < 32; j++)
        o = fmaf(fmaxf(acc2[j], 0.0f), W3[j], o);
    out[e] = o;
}

// ---------------- launch ----------------
extern "C" void kernel_launch(void* const* d_in, const int* in_sizes, int n_in,
                              void* d_out, int out_size, void* d_ws, size_t ws_size,
                              hipStream_t stream) {
    const float* x      = (const float*)d_in[0];
    const int*   ei     = (const int*)d_in[1];
    const float* attr   = (const float*)d_in[2];
    const float* conv_w = (const float*)d_in[3];
    const float* conv_b = (const float*)d_in[4];
    const float* ln_g   = (const float*)d_in[5];
    const float* ln_b   = (const float*)d_in[6];
    const float* dw1    = (const float*)d_in[7];
    const float* db1    = (const float*)d_in[8];
    const float* dw2    = (const float*)d_in[9];
    const float* db2    = (const float*)d_in[10];
    const float* dw3    = (const float*)d_in[11];
    const float* db3    = (const float*)d_in[12];
    float* out = (float*)d_out;

    const int* src = ei;
    const int* dst = ei + N_EDGES;

    char* p = (char*)d_ws;
    float*  dinv    = (float*)p;  p += sizeof(float) * N_NODES;
    float*  agg     = (float*)p;  p += sizeof(float) * (size_t)N_NODES * 64;
    float*  h3      = (float*)p;  p += sizeof(float) * (size_t)N_NODES * 64;
    __half* xsA     = (__half*)p; p += sizeof(__half) * (size_t)N_NODES * 32;
    __half* xsB     = (__half*)p; p += sizeof(__half) * (size_t)N_NODES * 32;
    __half* P_h     = (__half*)p; p += sizeof(__half) * (size_t)N_NODES * 64;
    __half* Q_h     = (__half*)p; p += sizeof(__half) * (size_t)N_NODES * 64;
    int*    cnt     = (int*)p;    p += sizeof(int) * N_NODES;
    int*    cursor  = (int*)p;    p += sizeof(int) * N_NODES;
    int*    row_ptr = (int*)p;    p += sizeof(int) * (N_NODES + 1);
    int*    col     = (int*)p;    p += sizeof(int) * N_EDGES;
    int*    bsum    = (int*)p;    p += sizeof(int) * 256;
    int*    boff    = (int*)p;    p += sizeof(int) * 256;

    const int nb_nodes = (N_NODES + 255) / 256;
    const int nb_edges = (N_EDGES + 255) / 256;
    const int nb_elems = (N_NODES * 64 + 255) / 256;

    k_zero_cnt<<<nb_nodes, 256, 0, stream>>>(cnt);
    k_count<<<nb_edges, 256, 0, stream>>>(dst, cnt);
    k_scan1<<<SCAN_BLOCKS, 256, 0, stream>>>(cnt, row_ptr, bsum, dinv);
    k_scan2<<<1, 256, 0, stream>>>(bsum, boff);
    k_scan3<<<nb_nodes, 256, 0, stream>>>(row_ptr, boff, cursor);
    k_fill<<<nb_edges, 256, 0, stream>>>(src, dst, cursor, col);
    k_xs_init<<<nb_elems, 256, 0, stream>>>(x, dinv, xsA, xsB);

    const int gemm_blocks = 1024;
    const int gather_blocks = 2 * (N_NODES / 4);   // (node,half) pairs, 4 waves/block

    for (int l = 0; l < 3; l++) {
        k_gather_agg<<<gather_blocks, 256, 0, stream>>>(xsA, xsB, dinv, row_ptr, col, agg);
        bool last = (l == 2);
        k_gemm_ln<<<gemm_blocks, 256, 0, stream>>>(
            agg, conv_w + l * 4096, conv_b + l * 64,
            ln_g + l * 64, ln_b + l * 64, dinv,
            last ? (__half*)nullptr : xsA, last ? (__half*)nullptr : xsB,
            last ? h3 : (float*)nullptr);
    }

    // P = h3 @ W1[0:64] + b1 ; Q = h3 @ W1[64:128]  (fp16 outputs, one dispatch)
    k_gemm_pq<<<2 * gemm_blocks, 256, 0, stream>>>(h3, dw1, db1, dw1 + 64 * 64, P_h, Q_h);

    k_decoder<<<nb_edges, 256, 0, stream>>>(
        P_h, Q_h, src, dst, attr, dw1 + 128 * 64, dw2, db2, dw3, db3, out);
}

// Round 11
// 455.523 us; speedup vs baseline: 1.1825x; 1.1825x over previous
//
#include <hip/hip_runtime.h>
#include <hip/hip_fp16.h>

#define N_NODES 50000
#define N_EDGES 800000
#define HID 64
#define F_EDGE 16
#define LN_EPS 1e-5f
#define SCAN_BLOCKS ((N_NODES + 255) / 256)   // 196

typedef _Float16 h2n __attribute__((ext_vector_type(2)));

__device__ inline h2n to_n(__half2 v) {
    union { __half2 a; h2n b; } u; u.a = v; return u.b;
}
__device__ inline h2n pack2(float x, float y) {
    h2n r; r.x = (_Float16)x; r.y = (_Float16)y; return r;
}

// ---------------- utility: 64-lane wave reduction ----------------
__device__ inline float wave_sum64(float v) {
    #pragma unroll
    for (int o = 32; o > 0; o >>= 1) v += __shfl_xor(v, o, 64);
    return v;
}

// ---------------- CSR build ----------------
__global__ void k_zero_cnt(int* __restrict__ cnt) {
    int i = blockIdx.x * blockDim.x + threadIdx.x;
    if (i < N_NODES) cnt[i] = 0;
}

__global__ void k_count(const int* __restrict__ dst, int* __restrict__ cnt) {
    int e = blockIdx.x * blockDim.x + threadIdx.x;
    if (e < N_EDGES) atomicAdd(&cnt[dst[e]], 1);
}

// stage 1: per-block exclusive scan into row_ptr, block sums into bsum; fused dinv
__global__ void k_scan1(const int* __restrict__ cnt, int* __restrict__ row_ptr,
                        int* __restrict__ bsum, float* __restrict__ dinv) {
    __shared__ int wsum[4];
    int tid = threadIdx.x, lane = tid & 63, w = tid >> 6;
    int i = blockIdx.x * 256 + tid;
    int v = (i < N_NODES) ? cnt[i] : 0;
    if (i < N_NODES) dinv[i] = rsqrtf((float)v + 1.0f);
    int isc = v;
    #pragma unroll
    for (int o = 1; o < 64; o <<= 1) {
        int n = __shfl_up(isc, o, 64);
        if (lane >= o) isc += n;
    }
    if (lane == 63) wsum[w] = isc;
    __syncthreads();
    int woff = 0;
    #pragma unroll
    for (int k = 0; k < 4; k++) woff += (k < w) ? wsum[k] : 0;
    if (i < N_NODES) row_ptr[i] = woff + isc - v;
    if (tid == 255) bsum[blockIdx.x] = woff + isc;
}

// stage 2: single block scans the block sums -> exclusive boff
__global__ void k_scan2(const int* __restrict__ bsum, int* __restrict__ boff) {
    __shared__ int wsum[4];
    int tid = threadIdx.x, lane = tid & 63, w = tid >> 6;
    int v = (tid < SCAN_BLOCKS) ? bsum[tid] : 0;
    int isc = v;
    #pragma unroll
    for (int o = 1; o < 64; o <<= 1) {
        int n = __shfl_up(isc, o, 64);
        if (lane >= o) isc += n;
    }
    if (lane == 63) wsum[w] = isc;
    __syncthreads();
    int woff = 0;
    #pragma unroll
    for (int k = 0; k < 4; k++) woff += (k < w) ? wsum[k] : 0;
    if (tid < SCAN_BLOCKS) boff[tid] = woff + isc - v;
}

// stage 3: apply block offsets, init cursor
__global__ void k_scan3(int* __restrict__ row_ptr, const int* __restrict__ boff,
                        int* __restrict__ cursor) {
    int i = blockIdx.x * blockDim.x + threadIdx.x;
    if (i < N_NODES) {
        int r = row_ptr[i] + boff[i >> 8];
        row_ptr[i] = r;
        cursor[i] = r;
    }
    if (i == 0) row_ptr[N_NODES] = N_EDGES;
}

// fill: single random 4B store per edge
__global__ void k_fill(const int* __restrict__ src, const int* __restrict__ dst,
                       int* __restrict__ cursor, int* __restrict__ col) {
    int e = blockIdx.x * blockDim.x + threadIdx.x;
    if (e < N_EDGES) {
        int s = src[e], d = dst[e];
        int pos = atomicAdd(&cursor[d], 1);
        col[pos] = s;
    }
}

// ---------------- xs = fp16(dinv * x) ----------------
__global__ void k_xs_init(const float* __restrict__ x, const float* __restrict__ dinv,
                          __half* __restrict__ xs) {
    int i = blockIdx.x * blockDim.x + threadIdx.x;
    if (i < N_NODES * 64) xs[i] = __float2half_rn(x[i] * dinv[i >> 6]);
}

// ---------------- prep: pack decoder weights into k-paired half2 tables ----------------
// w1cp[k2*64+j] = (W1c[2k2][j], W1c[2k2+1][j])   k2 in [0,8)
// w2p [k2*32+j] = (W2 [2k2][j], W2 [2k2+1][j])   k2 in [0,32)
__global__ void k_prep(const float* __restrict__ W1c, const float* __restrict__ W2,
                       __half2* __restrict__ w1cp, __half2* __restrict__ w2p) {
    int t = threadIdx.x;
    for (int i = t; i < 8 * 64; i += 256) {
        int k2 = i >> 6, j = i & 63;
        w1cp[i] = __floats2half2_rn(W1c[(2 * k2) * 64 + j], W1c[(2 * k2 + 1) * 64 + j]);
    }
    for (int i = t; i < 32 * 32; i += 256) {
        int k2 = i >> 5, j = i & 31;
        w2p[i] = __floats2half2_rn(W2[(2 * k2) * 32 + j], W2[(2 * k2 + 1) * 32 + j]);
    }
}

// ---------------- gather: agg[d] = dinv[d] * (sum_{s in N(d)} xs[s] + xs[d]) ----------------
// wave per node; 8 edge-slots x 8 lanes x 16 B (8 halves = full 128 B row/slot)
__global__ void __launch_bounds__(256)
k_gather_agg(const __half* __restrict__ xs, const float* __restrict__ dinv,
             const int* __restrict__ row_ptr, const int* __restrict__ col,
             float* __restrict__ agg) {
    int gid = blockIdx.x * blockDim.x + threadIdx.x;
    int node = gid >> 6, lane = gid & 63;
    if (node >= N_NODES) return;
    int n0 = __builtin_amdgcn_readfirstlane(node);
    int q = lane >> 3;        // edge slot 0..7
    int c8 = lane & 7;        // channel-octet (channels 8*c8..8*c8+7)
    const float4* x4 = (const float4*)xs;   // 16 B = 8 halves

    float acc[8];
    #pragma unroll
    for (int u = 0; u < 8; u++) acc[u] = 0.0f;

    // self-loop row on slot 0 (weight 1: xs is pre-scaled by dinv)
    if (q == 0) {
        float4 raw = x4[(size_t)n0 * 8 + c8];
        const __half2* hp = (const __half2*)&raw;
        float2 f0 = __half22float2(hp[0]);
        float2 f1 = __half22float2(hp[1]);
        float2 f2 = __half22float2(hp[2]);
        float2 f3 = __half22float2(hp[3]);
        acc[0] = f0.x; acc[1] = f0.y; acc[2] = f1.x; acc[3] = f1.y;
        acc[4] = f2.x; acc[5] = f2.y; acc[6] = f3.x; acc[7] = f3.y;
    }

    int beg = row_ptr[n0], end = row_ptr[n0 + 1];
    int deg = end - beg;

    int cL = 0;
    if (lane < deg) cL = col[beg + lane];
    int steps = (min(deg, 64) + 7) >> 3;

    #pragma unroll 4
    for (int st = 0; st < steps; st++) {
        int idx = 8 * st + q;
        int s = __shfl(cL, idx, 64);               // 0 for masked lanes -> safe addr
        float m = (idx < deg) ? 1.0f : 0.0f;
        float4 raw = x4[(size_t)s * 8 + c8];
        const __half2* hp = (const __half2*)&raw;
        float2 f0 = __half22float2(hp[0]);
        float2 f1 = __half22float2(hp[1]);
        float2 f2 = __half22float2(hp[2]);
        float2 f3 = __half22float2(hp[3]);
        acc[0] = fmaf(f0.x, m, acc[0]); acc[1] = fmaf(f0.y, m, acc[1]);
        acc[2] = fmaf(f1.x, m, acc[2]); acc[3] = fmaf(f1.y, m, acc[3]);
        acc[4] = fmaf(f2.x, m, acc[4]); acc[5] = fmaf(f2.y, m, acc[5]);
        acc[6] = fmaf(f3.x, m, acc[6]); acc[7] = fmaf(f3.y, m, acc[7]);
    }
    // tail deg>64 (rare)
    for (int j = beg + 64 + q; j < end; j += 8) {
        int s = col[j];
        float4 raw = x4[(size_t)s * 8 + c8];
        const __half2* hp = (const __half2*)&raw;
        float2 f0 = __half22float2(hp[0]);
        float2 f1 = __half22float2(hp[1]);
        float2 f2 = __half22float2(hp[2]);
        float2 f3 = __half22float2(hp[3]);
        acc[0] += f0.x; acc[1] += f0.y; acc[2] += f1.x; acc[3] += f1.y;
        acc[4] += f2.x; acc[5] += f2.y; acc[6] += f3.x; acc[7] += f3.y;
    }

    // reduce across the 8 slots (lane bits 3,4,5)
    #pragma unroll
    for (int o = 8; o <= 32; o <<= 1) {
        #pragma unroll
        for (int u = 0; u < 8; u++) acc[u] += __shfl_xor(acc[u], o, 64);
    }

    if (q == 0) {
        float di = dinv[n0];
        float4 y0, y1;
        y0.x = acc[0] * di; y0.y = acc[1] * di; y0.z = acc[2] * di; y0.w = acc[3] * di;
        y1.x = acc[4] * di; y1.y = acc[5] * di; y1.z = acc[6] * di; y1.w = acc[7] * di;
        float4* a4 = (float4*)agg;
        a4[(size_t)n0 * 16 + 2 * c8] = y0;
        a4[(size_t)n0 * 16 + 2 * c8 + 1] = y1;
    }
}

// ---------------- fused: y = relu(LN(agg @ W + cb)); out fp16 xs or fp32 h ----------------
__global__ void __launch_bounds__(256)
k_gemm_ln(const float* __restrict__ agg, const float* __restrict__ W,
          const float* __restrict__ cb, const float* __restrict__ g,
          const float* __restrict__ b, const float* __restrict__ dinv,
          __half* __restrict__ xs_out, float* __restrict__ h_out) {
    int lane = threadIdx.x & 63;
    int wid = (blockIdx.x * blockDim.x + threadIdx.x) >> 6;
    int nwaves = (gridDim.x * blockDim.x) >> 6;
    float w[64];
    #pragma unroll
    for (int k = 0; k < 64; k++) w[k] = W[k * 64 + lane];
    float cbl = cb[lane], gl = g[lane], bl = b[lane];
    for (int row = wid; row < N_NODES; row += nwaves) {
        int r = __builtin_amdgcn_readfirstlane(row);
        const float* xr = agg + r * 64;
        float acc = cbl;
        #pragma unroll
        for (int k = 0; k < 64; k++) acc = fmaf(xr[k], w[k], acc);
        float mu = wave_sum64(acc) * (1.0f / 64.0f);
        float d = acc - mu;
        float var = wave_sum64(d * d) * (1.0f / 64.0f);
        float y = fmaxf(fmaf(d * rsqrtf(var + LN_EPS), gl, bl), 0.0f);
        if (xs_out) {
            xs_out[r * 64 + lane] = __float2half_rn(y * dinv[r]);
        } else {
            h_out[r * 64 + lane] = y;
        }
    }
}

// fused P/Q (fp16 out): first half of blocks -> P = h@W1a + b1, second half -> Q = h@W1b
__global__ void __launch_bounds__(256)
k_gemm_pq(const float* __restrict__ hin, const float* __restrict__ Wp,
          const float* __restrict__ bp, const float* __restrict__ Wq,
          __half* __restrict__ P, __half* __restrict__ Q) {
    int half_g = gridDim.x >> 1;
    bool isQ = (blockIdx.x >= half_g);
    const float* W = isQ ? Wq : Wp;
    __half* out = isQ ? Q : P;
    int lane = threadIdx.x & 63;
    int bid = isQ ? (blockIdx.x - half_g) : blockIdx.x;
    int wid = (bid * blockDim.x + threadIdx.x) >> 6;
    int nwaves = (half_g * blockDim.x) >> 6;
    float w[64];
    #pragma unroll
    for (int k = 0; k < 64; k++) w[k] = W[k * 64 + lane];
    float binit = isQ ? 0.0f : bp[lane];
    for (int row = wid; row < N_NODES; row += nwaves) {
        int r = __builtin_amdgcn_readfirstlane(row);
        const float* xr = hin + r * 64;
        float acc = binit;
        #pragma unroll
        for (int k = 0; k < 64; k++) acc = fmaf(xr[k], w[k], acc);
        out[r * 64 + lane] = __float2half_rn(acc);
    }
}

// ---------------- decoder: edge order; fp16 P/Q; fdot2 (fp32-accum) MLP ----------------
// RULE: acc[]/acc2[] indices compile-time constant (no scratch spill).
__global__ void __launch_bounds__(256)
k_decoder(const __half* __restrict__ P, const __half* __restrict__ Q,
          const int* __restrict__ src, const int* __restrict__ dst,
          const float* __restrict__ attr,
          const __half2* __restrict__ w1cp,
          const __half2* __restrict__ w2p, const float* __restrict__ b2,
          const float* __restrict__ W3, const float* __restrict__ b3,
          float* __restrict__ out) {
    int e = blockIdx.x * blockDim.x + threadIdx.x;
    if (e >= N_EDGES) return;
    int s = src[e], d = dst[e];

    const float4* ap = (const float4*)(attr + (size_t)e * 16);
    float4 av0 = ap[0], av1 = ap[1], av2 = ap[2], av3 = ap[3];
    h2n a2[8];
    a2[0] = pack2(av0.x, av0.y); a2[1] = pack2(av0.z, av0.w);
    a2[2] = pack2(av1.x, av1.y); a2[3] = pack2(av1.z, av1.w);
    a2[4] = pack2(av2.x, av2.y); a2[5] = pack2(av2.z, av2.w);
    a2[6] = pack2(av3.x, av3.y); a2[7] = pack2(av3.z, av3.w);

    // acc = P[s] + Q[d] (fp16 rows, 128 B each: 8 x float4), fp32 accum
    float acc[64];
    const float4* Pp = (const float4*)(P + (size_t)s * 64);
    const float4* Qp = (const float4*)(Q + (size_t)d * 64);
    #pragma unroll
    for (int c = 0; c < 8; c++) {
        float4 pv = Pp[c], qv = Qp[c];
        const __half2* ph = (const __half2*)&pv;
        const __half2* qh = (const __half2*)&qv;
        #pragma unroll
        for (int u = 0; u < 4; u++) {
            float2 pf = __half22float2(ph[u]);
            float2 qf = __half22float2(qh[u]);
            acc[8 * c + 2 * u]     = pf.x + qf.x;
            acc[8 * c + 2 * u + 1] = pf.y + qf.y;
        }
    }

    // + attr @ W1c via fdot2 (k-paired): acc[j] += dot2(a2[k2], w1cp[k2*64+j])
    #pragma unroll
    for (int k2 = 0; k2 < 8; k2++) {
        #pragma unroll
        for (int j = 0; j < 64; j++)
            acc[j] = __builtin_amdgcn_fdot2(a2[k2], to_n(w1cp[k2 * 64 + j]), acc[j], false);
    }

    // relu + pack h into k-paired half2
    h2n hh[32];
    #pragma unroll
    for (int k2 = 0; k2 < 32; k2++)
        hh[k2] = pack2(fmaxf(acc[2 * k2], 0.0f), fmaxf(acc[2 * k2 + 1], 0.0f));

    // layer 2 via fdot2: acc2[j] += dot2(hh[k2], w2p[k2*32+j])
    float acc2[32];
    #pragma unroll
    for (int j = 0; j < 32; j++) acc2[j] = b2[j];
    #pragma unroll
    for (int k2 = 0; k2 < 32; k2++) {
        #pragma unroll
        for (int j = 0; j < 32; j++)
            acc2[j] = __builtin_amdgcn_fdot2(hh[k2], to_n(w2p[k2 * 32 + j]), acc2[j], false);
    }

    // layer 3 (fp32)
    float o = b3[0];
    #pragma unroll
    for (int j = 0; j < 32; j++)
        o = fmaf(fmaxf(acc2[j], 0.0f), W3[j], o);
    out[e] = o;
}

// ---------------- launch ----------------
extern "C" void kernel_launch(void* const* d_in, const int* in_sizes, int n_in,
                              void* d_out, int out_size, void* d_ws, size_t ws_size,
                              hipStream_t stream) {
    const float* x      = (const float*)d_in[0];
    const int*   ei     = (const int*)d_in[1];
    const float* attr   = (const float*)d_in[2];
    const float* conv_w = (const float*)d_in[3];
    const float* conv_b = (const float*)d_in[4];
    const float* ln_g   = (const float*)d_in[5];
    const float* ln_b   = (const float*)d_in[6];
    const float* dw1    = (const float*)d_in[7];
    const float* db1    = (const float*)d_in[8];
    const float* dw2    = (const float*)d_in[9];
    const float* db2    = (const float*)d_in[10];
    const float* dw3    = (const float*)d_in[11];
    const float* db3    = (const float*)d_in[12];
    float* out = (float*)d_out;

    const int* src = ei;
    const int* dst = ei + N_EDGES;

    char* p = (char*)d_ws;
    float*   dinv    = (float*)p;   p += sizeof(float) * N_NODES;
    float*   agg     = (float*)p;   p += sizeof(float) * (size_t)N_NODES * 64;
    float*   h3      = (float*)p;   p += sizeof(float) * (size_t)N_NODES * 64;
    __half*  xs      = (__half*)p;  p += sizeof(__half) * (size_t)N_NODES * 64;
    __half*  P_h     = (__half*)p;  p += sizeof(__half) * (size_t)N_NODES * 64;
    __half*  Q_h     = (__half*)p;  p += sizeof(__half) * (size_t)N_NODES * 64;
    int*     cnt     = (int*)p;     p += sizeof(int) * N_NODES;
    int*     cursor  = (int*)p;     p += sizeof(int) * N_NODES;
    int*     row_ptr = (int*)p;     p += sizeof(int) * (N_NODES + 1);
    int*     col     = (int*)p;     p += sizeof(int) * N_EDGES;
    int*     bsum    = (int*)p;     p += sizeof(int) * 256;
    int*     boff    = (int*)p;     p += sizeof(int) * 256;
    __half2* w1cp    = (__half2*)p; p += sizeof(__half2) * 8 * 64;
    __half2* w2p     = (__half2*)p; p += sizeof(__half2) * 32 * 32;

    const int nb_nodes = (N_NODES + 255) / 256;
    const int nb_edges = (N_EDGES + 255) / 256;
    const int nb_elems = (N_NODES * 64 + 255) / 256;

    k_zero_cnt<<<nb_nodes, 256, 0, stream>>>(cnt);
    k_count<<<nb_edges, 256, 0, stream>>>(dst, cnt);
    k_scan1<<<SCAN_BLOCKS, 256, 0, stream>>>(cnt, row_ptr, bsum, dinv);
    k_scan2<<<1, 256, 0, stream>>>(bsum, boff);
    k_scan3<<<nb_nodes, 256, 0, stream>>>(row_ptr, boff, cursor);
    k_fill<<<nb_edges, 256, 0, stream>>>(src, dst, cursor, col);
    k_xs_init<<<nb_elems, 256, 0, stream>>>(x, dinv, xs);
    k_prep<<<1, 256, 0, stream>>>(dw1 + 128 * 64, dw2, w1cp, w2p);

    const int gemm_blocks = 1024;
    const int gather_blocks = N_NODES / 4;   // wave per node, 4 waves/block

    for (int l = 0; l < 3; l++) {
        k_gather_agg<<<gather_blocks, 256, 0, stream>>>(xs, dinv, row_ptr, col, agg);
        bool last = (l == 2);
        k_gemm_ln<<<gemm_blocks, 256, 0, stream>>>(
            agg, conv_w + l * 4096, conv_b + l * 64,
            ln_g + l * 64, ln_b + l * 64, dinv,
            last ? (__half*)nullptr : xs, last ? h3 : (float*)nullptr);
    }

    // P = h3 @ W1[0:64] + b1 ; Q = h3 @ W1[64:128]  (fp16 outputs, one dispatch)
    k_gemm_pq<<<2 * gemm_blocks, 256, 0, stream>>>(h3, dw1, db1, dw1 + 64 * 64, P_h, Q_h);

    k_decoder<<<nb_edges, 256, 0, stream>>>(
        P_h, Q_h, src, dst, attr, w1cp, w2p, db2, dw3, db3, out);
}

// Round 12
// 451.329 us; speedup vs baseline: 1.1935x; 1.0093x over previous
//
#include <hip/hip_runtime.h>
#include <hip/hip_fp16.h>

#define N_NODES 50000
#define N_EDGES 800000
#define HID 64
#define F_EDGE 16
#define LN_EPS 1e-5f
#define SCAN_BLOCKS ((N_NODES + 255) / 256)   // 196

typedef _Float16 h2n __attribute__((ext_vector_type(2)));

__device__ inline h2n to_n(__half2 v) {
    union { __half2 a; h2n b; } u; u.a = v; return u.b;
}
__device__ inline h2n pack2(float x, float y) {
    h2n r; r.x = (_Float16)x; r.y = (_Float16)y; return r;
}

// ---------------- utility: 64-lane wave reduction ----------------
__device__ inline float wave_sum64(float v) {
    #pragma unroll
    for (int o = 32; o > 0; o >>= 1) v += __shfl_xor(v, o, 64);
    return v;
}

// ---------------- CSR build ----------------
__global__ void k_zero_cnt(int* __restrict__ cnt) {
    int i = blockIdx.x * blockDim.x + threadIdx.x;
    if (i < N_NODES) cnt[i] = 0;
}

__global__ void k_count(const int* __restrict__ dst, int* __restrict__ cnt) {
    int e = blockIdx.x * blockDim.x + threadIdx.x;
    if (e < N_EDGES) atomicAdd(&cnt[dst[e]], 1);
}

// stage 1: per-block exclusive scan into row_ptr, block sums into bsum; fused dinv
__global__ void k_scan1(const int* __restrict__ cnt, int* __restrict__ row_ptr,
                        int* __restrict__ bsum, float* __restrict__ dinv) {
    __shared__ int wsum[4];
    int tid = threadIdx.x, lane = tid & 63, w = tid >> 6;
    int i = blockIdx.x * 256 + tid;
    int v = (i < N_NODES) ? cnt[i] : 0;
    if (i < N_NODES) dinv[i] = rsqrtf((float)v + 1.0f);
    int isc = v;
    #pragma unroll
    for (int o = 1; o < 64; o <<= 1) {
        int n = __shfl_up(isc, o, 64);
        if (lane >= o) isc += n;
    }
    if (lane == 63) wsum[w] = isc;
    __syncthreads();
    int woff = 0;
    #pragma unroll
    for (int k = 0; k < 4; k++) woff += (k < w) ? wsum[k] : 0;
    if (i < N_NODES) row_ptr[i] = woff + isc - v;
    if (tid == 255) bsum[blockIdx.x] = woff + isc;
}

// stage 2 (+ decoder weight prep fused): single block
// w1cp[k2*64+j] = (W1c[2k2][j], W1c[2k2+1][j])   k2 in [0,8)
// w2p [k2*32+j] = (W2 [2k2][j], W2 [2k2+1][j])   k2 in [0,32)
__global__ void k_scan2_prep(const int* __restrict__ bsum, int* __restrict__ boff,
                             const float* __restrict__ W1c, const float* __restrict__ W2,
                             __half2* __restrict__ w1cp, __half2* __restrict__ w2p) {
    __shared__ int wsum[4];
    int tid = threadIdx.x, lane = tid & 63, w = tid >> 6;
    int v = (tid < SCAN_BLOCKS) ? bsum[tid] : 0;
    int isc = v;
    #pragma unroll
    for (int o = 1; o < 64; o <<= 1) {
        int n = __shfl_up(isc, o, 64);
        if (lane >= o) isc += n;
    }
    if (lane == 63) wsum[w] = isc;
    __syncthreads();
    int woff = 0;
    #pragma unroll
    for (int k = 0; k < 4; k++) woff += (k < w) ? wsum[k] : 0;
    if (tid < SCAN_BLOCKS) boff[tid] = woff + isc - v;
    // ---- prep (independent of scan) ----
    for (int i = tid; i < 8 * 64; i += 256) {
        int k2 = i >> 6, j = i & 63;
        w1cp[i] = __floats2half2_rn(W1c[(2 * k2) * 64 + j], W1c[(2 * k2 + 1) * 64 + j]);
    }
    for (int i = tid; i < 32 * 32; i += 256) {
        int k2 = i >> 5, j = i & 31;
        w2p[i] = __floats2half2_rn(W2[(2 * k2) * 32 + j], W2[(2 * k2 + 1) * 32 + j]);
    }
}

// stage 3: apply block offsets, init cursor
__global__ void k_scan3(int* __restrict__ row_ptr, const int* __restrict__ boff,
                        int* __restrict__ cursor) {
    int i = blockIdx.x * blockDim.x + threadIdx.x;
    if (i < N_NODES) {
        int r = row_ptr[i] + boff[i >> 8];
        row_ptr[i] = r;
        cursor[i] = r;
    }
    if (i == 0) row_ptr[N_NODES] = N_EDGES;
}

// fill: single random 4B store per edge
__global__ void k_fill(const int* __restrict__ src, const int* __restrict__ dst,
                       int* __restrict__ cursor, int* __restrict__ col) {
    int e = blockIdx.x * blockDim.x + threadIdx.x;
    if (e < N_EDGES) {
        int s = src[e], d = dst[e];
        int pos = atomicAdd(&cursor[d], 1);
        col[pos] = s;
    }
}

// ---------------- xs = fp16(dinv * x) ----------------
__global__ void k_xs_init(const float* __restrict__ x, const float* __restrict__ dinv,
                          __half* __restrict__ xs) {
    int i = blockIdx.x * blockDim.x + threadIdx.x;
    if (i < N_NODES * 64) xs[i] = __float2half_rn(x[i] * dinv[i >> 6]);
}

// ---------------- gather: 2 adjacent nodes per wave, interleaved streams ----------------
// agg[d] = dinv[d] * (sum_{s in N(d)} xs[s] + xs[d]); xs pre-scaled by dinv.
// 8 edge-slots x 8 lanes x 16 B per node-stream; A and B streams independent.
__global__ void __launch_bounds__(256)
k_gather_agg(const __half* __restrict__ xs, const float* __restrict__ dinv,
             const int* __restrict__ row_ptr, const int* __restrict__ col,
             float* __restrict__ agg) {
    int gid = blockIdx.x * blockDim.x + threadIdx.x;
    int wid = gid >> 6, lane = gid & 63;
    int nA = wid * 2;
    if (nA >= N_NODES) return;
    nA = __builtin_amdgcn_readfirstlane(nA);
    int nB = nA + 1;                       // N_NODES even -> always valid
    int q = lane >> 3;                     // edge slot 0..7
    int c8 = lane & 7;                     // channel-octet
    const float4* x4 = (const float4*)xs;  // 16 B = 8 halves

    float accA[8], accB[8];
    #pragma unroll
    for (int u = 0; u < 8; u++) { accA[u] = 0.0f; accB[u] = 0.0f; }

    // self-loop rows: slot 0 -> node A, slot 1 -> node B (any slot ok: reduced later)
    if (q == 0) {
        float4 raw = x4[(size_t)nA * 8 + c8];
        const __half2* hp = (const __half2*)&raw;
        float2 f0 = __half22float2(hp[0]);
        float2 f1 = __half22float2(hp[1]);
        float2 f2 = __half22float2(hp[2]);
        float2 f3 = __half22float2(hp[3]);
        accA[0] = f0.x; accA[1] = f0.y; accA[2] = f1.x; accA[3] = f1.y;
        accA[4] = f2.x; accA[5] = f2.y; accA[6] = f3.x; accA[7] = f3.y;
    } else if (q == 1) {
        float4 raw = x4[(size_t)nB * 8 + c8];
        const __half2* hp = (const __half2*)&raw;
        float2 f0 = __half22float2(hp[0]);
        float2 f1 = __half22float2(hp[1]);
        float2 f2 = __half22float2(hp[2]);
        float2 f3 = __half22float2(hp[3]);
        accB[0] = f0.x; accB[1] = f0.y; accB[2] = f1.x; accB[3] = f1.y;
        accB[4] = f2.x; accB[5] = f2.y; accB[6] = f3.x; accB[7] = f3.y;
    }

    int begA = row_ptr[nA];
    int begB = row_ptr[nA + 1];           // = endA (CSR contiguity)
    int endB = row_ptr[nA + 2];
    int degA = begB - begA;
    int degB = endB - begB;

    int cLA = 0, cLB = 0;
    if (lane < degA) cLA = col[begA + lane];
    if (lane < degB) cLB = col[begB + lane];
    int stepsA = (min(degA, 64) + 7) >> 3;
    int stepsB = (min(degB, 64) + 7) >> 3;
    int steps = max(stepsA, stepsB);

    #pragma unroll 2
    for (int st = 0; st < steps; st++) {
        int idx = 8 * st + q;
        int sA = __shfl(cLA, idx, 64);             // 0 for masked -> safe addr
        int sB = __shfl(cLB, idx, 64);
        float mA = (idx < degA) ? 1.0f : 0.0f;
        float mB = (idx < degB) ? 1.0f : 0.0f;
        float4 rA = x4[(size_t)sA * 8 + c8];
        float4 rB = x4[(size_t)sB * 8 + c8];
        const __half2* ha = (const __half2*)&rA;
        const __half2* hb = (const __half2*)&rB;
        float2 a0 = __half22float2(ha[0]), a1 = __half22float2(ha[1]);
        float2 a2 = __half22float2(ha[2]), a3 = __half22float2(ha[3]);
        float2 b0 = __half22float2(hb[0]), b1 = __half22float2(hb[1]);
        float2 b2 = __half22float2(hb[2]), b3 = __half22float2(hb[3]);
        accA[0] = fmaf(a0.x, mA, accA[0]); accA[1] = fmaf(a0.y, mA, accA[1]);
        accA[2] = fmaf(a1.x, mA, accA[2]); accA[3] = fmaf(a1.y, mA, accA[3]);
        accA[4] = fmaf(a2.x, mA, accA[4]); accA[5] = fmaf(a2.y, mA, accA[5]);
        accA[6] = fmaf(a3.x, mA, accA[6]); accA[7] = fmaf(a3.y, mA, accA[7]);
        accB[0] = fmaf(b0.x, mB, accB[0]); accB[1] = fmaf(b0.y, mB, accB[1]);
        accB[2] = fmaf(b1.x, mB, accB[2]); accB[3] = fmaf(b1.y, mB, accB[3]);
        accB[4] = fmaf(b2.x, mB, accB[4]); accB[5] = fmaf(b2.y, mB, accB[5]);
        accB[6] = fmaf(b3.x, mB, accB[6]); accB[7] = fmaf(b3.y, mB, accB[7]);
    }
    // tails deg>64 (rare)
    for (int j = begA + 64 + q; j < begB; j += 8) {
        int s = col[j];
        float4 raw = x4[(size_t)s * 8 + c8];
        const __half2* hp = (const __half2*)&raw;
        float2 f0 = __half22float2(hp[0]), f1 = __half22float2(hp[1]);
        float2 f2 = __half22float2(hp[2]), f3 = __half22float2(hp[3]);
        accA[0] += f0.x; accA[1] += f0.y; accA[2] += f1.x; accA[3] += f1.y;
        accA[4] += f2.x; accA[5] += f2.y; accA[6] += f3.x; accA[7] += f3.y;
    }
    for (int j = begB + 64 + q; j < endB; j += 8) {
        int s = col[j];
        float4 raw = x4[(size_t)s * 8 + c8];
        const __half2* hp = (const __half2*)&raw;
        float2 f0 = __half22float2(hp[0]), f1 = __half22float2(hp[1]);
        float2 f2 = __half22float2(hp[2]), f3 = __half22float2(hp[3]);
        accB[0] += f0.x; accB[1] += f0.y; accB[2] += f1.x; accB[3] += f1.y;
        accB[4] += f2.x; accB[5] += f2.y; accB[6] += f3.x; accB[7] += f3.y;
    }

    // reduce both streams across the 8 slots (lane bits 3,4,5) — chains interleave
    #pragma unroll
    for (int o = 8; o <= 32; o <<= 1) {
        #pragma unroll
        for (int u = 0; u < 8; u++) {
            accA[u] += __shfl_xor(accA[u], o, 64);
            accB[u] += __shfl_xor(accB[u], o, 64);
        }
    }

    if (q == 0) {
        float di = dinv[nA];
        float4 y0, y1;
        y0.x = accA[0] * di; y0.y = accA[1] * di; y0.z = accA[2] * di; y0.w = accA[3] * di;
        y1.x = accA[4] * di; y1.y = accA[5] * di; y1.z = accA[6] * di; y1.w = accA[7] * di;
        float4* a4 = (float4*)agg;
        a4[(size_t)nA * 16 + 2 * c8] = y0;
        a4[(size_t)nA * 16 + 2 * c8 + 1] = y1;
    } else if (q == 1) {
        float di = dinv[nB];
        float4 y0, y1;
        y0.x = accB[0] * di; y0.y = accB[1] * di; y0.z = accB[2] * di; y0.w = accB[3] * di;
        y1.x = accB[4] * di; y1.y = accB[5] * di; y1.z = accB[6] * di; y1.w = accB[7] * di;
        float4* a4 = (float4*)agg;
        a4[(size_t)nB * 16 + 2 * c8] = y0;
        a4[(size_t)nB * 16 + 2 * c8 + 1] = y1;
    }
}

// ---------------- fused: y = relu(LN(agg @ W + cb)); out fp16 xs or fp32 h ----------------
__global__ void __launch_bounds__(256)
k_gemm_ln(const float* __restrict__ agg, const float* __restrict__ W,
          const float* __restrict__ cb, const float* __restrict__ g,
          const float* __restrict__ b, const float* __restrict__ dinv,
          __half* __restrict__ xs_out, float* __restrict__ h_out) {
    int lane = threadIdx.x & 63;
    int wid = (blockIdx.x * blockDim.x + threadIdx.x) >> 6;
    int nwaves = (gridDim.x * blockDim.x) >> 6;
    float w[64];
    #pragma unroll
    for (int k = 0; k < 64; k++) w[k] = W[k * 64 + lane];
    float cbl = cb[lane], gl = g[lane], bl = b[lane];
    for (int row = wid; row < N_NODES; row += nwaves) {
        int r = __builtin_amdgcn_readfirstlane(row);
        const float* xr = agg + r * 64;
        float acc = cbl;
        #pragma unroll
        for (int k = 0; k < 64; k++) acc = fmaf(xr[k], w[k], acc);
        float mu = wave_sum64(acc) * (1.0f / 64.0f);
        float d = acc - mu;
        float var = wave_sum64(d * d) * (1.0f / 64.0f);
        float y = fmaxf(fmaf(d * rsqrtf(var + LN_EPS), gl, bl), 0.0f);
        if (xs_out) {
            xs_out[r * 64 + lane] = __float2half_rn(y * dinv[r]);
        } else {
            h_out[r * 64 + lane] = y;
        }
    }
}

// fused P/Q (fp16 out): first half of blocks -> P = h@W1a + b1, second half -> Q = h@W1b
__global__ void __launch_bounds__(256)
k_gemm_pq(const float* __restrict__ hin, const float* __restrict__ Wp,
          const float* __restrict__ bp, const float* __restrict__ Wq,
          __half* __restrict__ P, __half* __restrict__ Q) {
    int half_g = gridDim.x >> 1;
    bool isQ = (blockIdx.x >= half_g);
    const float* W = isQ ? Wq : Wp;
    __half* out = isQ ? Q : P;
    int lane = threadIdx.x & 63;
    int bid = isQ ? (blockIdx.x - half_g) : blockIdx.x;
    int wid = (bid * blockDim.x + threadIdx.x) >> 6;
    int nwaves = (half_g * blockDim.x) >> 6;
    float w[64];
    #pragma unroll
    for (int k = 0; k < 64; k++) w[k] = W[k * 64 + lane];
    float binit = isQ ? 0.0f : bp[lane];
    for (int row = wid; row < N_NODES; row += nwaves) {
        int r = __builtin_amdgcn_readfirstlane(row);
        const float* xr = hin + r * 64;
        float acc = binit;
        #pragma unroll
        for (int k = 0; k < 64; k++) acc = fmaf(xr[k], w[k], acc);
        out[r * 64 + lane] = __float2half_rn(acc);
    }
}

// ---------------- decoder: edge order; fp16 P/Q; fdot2 (fp32-accum) MLP ----------------
// RULE: acc[]/acc2[] indices compile-time constant (no scratch spill).
__global__ void __launch_bounds__(256)
k_decoder(const __half* __restrict__ P, const __half* __restrict__ Q,
          const int* __restrict__ src, const int* __restrict__ dst,
          const float* __restrict__ attr,
          const __half2* __restrict__ w1cp,
          const __half2* __restrict__ w2p, const float* __restrict__ b2,
          const float* __restrict__ W3, const float* __restrict__ b3,
          float* __restrict__ out) {
    int e = blockIdx.x * blockDim.x + threadIdx.x;
    if (e >= N_EDGES) return;
    int s = src[e], d = dst[e];

    const float4* ap = (const float4*)(attr + (size_t)e * 16);
    float4 av0 = ap[0], av1 = ap[1], av2 = ap[2], av3 = ap[3];
    h2n a2[8];
    a2[0] = pack2(av0.x, av0.y); a2[1] = pack2(av0.z, av0.w);
    a2[2] = pack2(av1.x, av1.y); a2[3] = pack2(av1.z, av1.w);
    a2[4] = pack2(av2.x, av2.y); a2[5] = pack2(av2.z, av2.w);
    a2[6] = pack2(av3.x, av3.y); a2[7] = pack2(av3.z, av3.w);

    // acc = P[s] + Q[d] (fp16 rows, 128 B each: 8 x float4), fp32 accum
    float acc[64];
    const float4* Pp = (const float4*)(P + (size_t)s * 64);
    const float4* Qp = (const float4*)(Q + (size_t)d * 64);
    #pragma unroll
    for (int c = 0; c < 8; c++) {
        float4 pv = Pp[c], qv = Qp[c];
        const __half2* ph = (const __half2*)&pv;
        const __half2* qh = (const __half2*)&qv;
        #pragma unroll
        for (int u = 0; u < 4; u++) {
            float2 pf = __half22float2(ph[u]);
            float2 qf = __half22float2(qh[u]);
            acc[8 * c + 2 * u]     = pf.x + qf.x;
            acc[8 * c + 2 * u + 1] = pf.y + qf.y;
        }
    }

    // + attr @ W1c via fdot2 (k-paired): acc[j] += dot2(a2[k2], w1cp[k2*64+j])
    #pragma unroll
    for (int k2 = 0; k2 < 8; k2++) {
        #pragma unroll
        for (int j = 0; j < 64; j++)
            acc[j] = __builtin_amdgcn_fdot2(a2[k2], to_n(w1cp[k2 * 64 + j]), acc[j], false);
    }

    // relu + pack h into k-paired half2
    h2n hh[32];
    #pragma unroll
    for (int k2 = 0; k2 < 32; k2++)
        hh[k2] = pack2(fmaxf(acc[2 * k2], 0.0f), fmaxf(acc[2 * k2 + 1], 0.0f));

    // layer 2 via fdot2
    float acc2[32];
    #pragma unroll
    for (int j = 0; j < 32; j++) acc2[j] = b2[j];
    #pragma unroll
    for (int k2 = 0; k2 < 32; k2++) {
        #pragma unroll
        for (int j = 0; j < 32; j++)
            acc2[j] = __builtin_amdgcn_fdot2(hh[k2], to_n(w2p[k2 * 32 + j]), acc2[j], false);
    }

    // layer 3 (fp32)
    float o = b3[0];
    #pragma unroll
    for (int j = 0; j < 32; j++)
        o = fmaf(fmaxf(acc2[j], 0.0f), W3[j], o);
    out[e] = o;
}

// ---------------- launch ----------------
extern "C" void kernel_launch(void* const* d_in, const int* in_sizes, int n_in,
                              void* d_out, int out_size, void* d_ws, size_t ws_size,
                              hipStream_t stream) {
    const float* x      = (const float*)d_in[0];
    const int*   ei     = (const int*)d_in[1];
    const float* attr   = (const float*)d_in[2];
    const float* conv_w = (const float*)d_in[3];
    const float* conv_b = (const float*)d_in[4];
    const float* ln_g   = (const float*)d_in[5];
    const float* ln_b   = (const float*)d_in[6];
    const float* dw1    = (const float*)d_in[7];
    const float* db1    = (const float*)d_in[8];
    const float* dw2    = (const float*)d_in[9];
    const float* db2    = (const float*)d_in[10];
    const float* dw3    = (const float*)d_in[11];
    const float* db3    = (const float*)d_in[12];
    float* out = (float*)d_out;

    const int* src = ei;
    const int* dst = ei + N_EDGES;

    char* p = (char*)d_ws;
    float*   dinv    = (float*)p;   p += sizeof(float) * N_NODES;
    float*   agg     = (float*)p;   p += sizeof(float) * (size_t)N_NODES * 64;
    float*   h3      = (float*)p;   p += sizeof(float) * (size_t)N_NODES * 64;
    __half*  xs      = (__half*)p;  p += sizeof(__half) * (size_t)N_NODES * 64;
    __half*  P_h     = (__half*)p;  p += sizeof(__half) * (size_t)N_NODES * 64;
    __half*  Q_h     = (__half*)p;  p += sizeof(__half) * (size_t)N_NODES * 64;
    int*     cnt     = (int*)p;     p += sizeof(int) * N_NODES;
    int*     cursor  = (int*)p;     p += sizeof(int) * N_NODES;
    int*     row_ptr = (int*)p;     p += sizeof(int) * (N_NODES + 1);
    int*     col     = (int*)p;     p += sizeof(int) * N_EDGES;
    int*     bsum    = (int*)p;     p += sizeof(int) * 256;
    int*     boff    = (int*)p;     p += sizeof(int) * 256;
    __half2* w1cp    = (__half2*)p; p += sizeof(__half2) * 8 * 64;
    __half2* w2p     = (__half2*)p; p += sizeof(__half2) * 32 * 32;

    const int nb_nodes = (N_NODES + 255) / 256;
    const int nb_edges = (N_EDGES + 255) / 256;
    const int nb_elems = (N_NODES * 64 + 255) / 256;

    k_zero_cnt<<<nb_nodes, 256, 0, stream>>>(cnt);
    k_count<<<nb_edges, 256, 0, stream>>>(dst, cnt);
    k_scan1<<<SCAN_BLOCKS, 256, 0, stream>>>(cnt, row_ptr, bsum, dinv);
    k_scan2_prep<<<1, 256, 0, stream>>>(bsum, boff, dw1 + 128 * 64, dw2, w1cp, w2p);
    k_scan3<<<nb_nodes, 256, 0, stream>>>(row_ptr, boff, cursor);
    k_fill<<<nb_edges, 256, 0, stream>>>(src, dst, cursor, col);
    k_xs_init<<<nb_elems, 256, 0, stream>>>(x, dinv, xs);

    const int gemm_blocks = 1024;
    const int gather_blocks = N_NODES / 8;   // 2 nodes/wave, 4 waves/block

    for (int l = 0; l < 3; l++) {
        k_gather_agg<<<gather_blocks, 256, 0, stream>>>(xs, dinv, row_ptr, col, agg);
        bool last = (l == 2);
        k_gemm_ln<<<gemm_blocks, 256, 0, stream>>>(
            agg, conv_w + l * 4096, conv_b + l * 64,
            ln_g + l * 64, ln_b + l * 64, dinv,
            last ? (__half*)nullptr : xs, last ? h3 : (float*)nullptr);
    }

    // P = h3 @ W1[0:64] + b1 ; Q = h3 @ W1[64:128]  (fp16 outputs, one dispatch)
    k_gemm_pq<<<2 * gemm_blocks, 256, 0, stream>>>(h3, dw1, db1, dw1 + 64 * 64, P_h, Q_h);

    k_decoder<<<nb_edges, 256, 0, stream>>>(
        P_h, Q_h, src, dst, attr, w1cp, w2p, db2, dw3, db3, out);
}